// Round 6
// baseline (77.682 us; speedup 1.0000x reference)
//
#include <hip/hip_runtime.h>

#define GH 32
#define GW 32
#define P  34              // 32 + 2 halo; halo stays INF forever (OOB + ring + backtrack)
#define NP (P * P)         // 1156, divisible by 4
#define INFV 1000000000.0f
#define EPSV 1e-6f

// One wave (64 lanes) per batch. Lane owns a 4x4 register tile:
// tr = tid>>3, tc = tid&7; origin (r0,c0) = (tr*4, tc*4).
// LDS d[34][34] = dist field with a permanent-INF halo (no boundary selects).
//
// Loop unit = { ring-read (14 LDS: 6x b64 + 8x b32) ; one 16-cell in-place
// Gauss-Seidel pass with border writes INLINED after each row/col (drain
// overlaps compute) ; barrier ; ballot exit-check }. Units cycle 4 raster
// orders: row-fwd, col-fwd, row-bwd, col-bwd. In-place register GS makes
// RELAX order-agnostic (processed neighbors are current, rest pre-pass);
// col orders make both down-(resp. up-)diagonals current together, so
// vertical-zigzag chains resolve in-tile in one unit.
//
// Exactness: every update is t = min(t, fl(w + v_n)), v_n a genuine float
// walk-sum from the source (register or ring snapshot; monotone, so any
// staleness only delays, never corrupts). Termination only after a unit in
// which NO cell improved: that unit checked all 8 neighbor inequalities of
// every cell at values unchanged throughout the unit => verified least
// fixed point = the reference's converged dist (weights>0 => simple optimal
// walks, <=1023 hops <= its 1024 Jacobi sweeps). Backtrack: same
// first-strict-min scan in OFFS order => identical path & tie-breaking.

#define NMIN8(ul,uu,ur,ll,rr,dl,dd,dr) \
    fminf(fminf(fminf(fminf((ul),(uu)),(ur)), fminf(fminf((ll),(rr)),(dl))), fminf((dd),(dr)))

#define RELAXC(i,j) {                                                         \
    const float ul = ((i)==0) ? top[(j)]   : (((j)==0) ? lft[(i)-1] : t[(i)-1][(j)-1]); \
    const float uu = ((i)==0) ? top[(j)+1] : t[(i)-1][(j)];                    \
    const float ur = ((i)==0) ? top[(j)+2] : (((j)==3) ? rgt[(i)-1] : t[(i)-1][(j)+1]); \
    const float ll = ((j)==0) ? lft[(i)]   : t[(i)][(j)-1];                    \
    const float rr = ((j)==3) ? rgt[(i)]   : t[(i)][(j)+1];                    \
    const float dl = ((i)==3) ? bot[(j)]   : (((j)==0) ? lft[(i)+1] : t[(i)+1][(j)-1]); \
    const float dd = ((i)==3) ? bot[(j)+1] : t[(i)+1][(j)];                    \
    const float dr = ((i)==3) ? bot[(j)+2] : (((j)==3) ? rgt[(i)+1] : t[(i)+1][(j)+1]); \
    const float old = t[(i)][(j)];                                            \
    const float nd  = w[(i)][(j)] + NMIN8(ul,uu,ur,ll,rr,dl,dd,dr);           \
    ch = ch || (nd < old);                                                    \
    t[(i)][(j)] = fminf(old, nd);                                             \
}

// ring read: top/bot rows are even-element-aligned (base-P-1 = r0*34+c0,
// base+4P-1 = (r0+5)*34+c0, both even) -> float2 (ds_read_b64)
#define RINGREAD {                                                            \
    const float2 t0 = *(const float2*)&d[base - P - 1];                       \
    const float2 t1 = *(const float2*)&d[base - P + 1];                       \
    const float2 t2 = *(const float2*)&d[base - P + 3];                       \
    top[0]=t0.x; top[1]=t0.y; top[2]=t1.x; top[3]=t1.y; top[4]=t2.x; top[5]=t2.y; \
    const float2 b0 = *(const float2*)&d[base + 4*P - 1];                     \
    const float2 b1 = *(const float2*)&d[base + 4*P + 1];                     \
    const float2 b2 = *(const float2*)&d[base + 4*P + 3];                     \
    bot[0]=b0.x; bot[1]=b0.y; bot[2]=b1.x; bot[3]=b1.y; bot[4]=b2.x; bot[5]=b2.y; \
    lft[0]=d[base-1];     lft[1]=d[base+P-1];   lft[2]=d[base+2*P-1]; lft[3]=d[base+3*P-1]; \
    rgt[0]=d[base+4];     rgt[1]=d[base+P+4];   rgt[2]=d[base+2*P+4]; rgt[3]=d[base+3*P+4]; \
}

#define WR(i,j) d[base + (i)*P + (j)] = t[i][j];

#define UNIT_ROWF { float top[6], bot[6], lft[4], rgt[4]; RINGREAD bool ch=false; \
  RELAXC(0,0) RELAXC(0,1) RELAXC(0,2) RELAXC(0,3) WR(0,0) WR(0,1) WR(0,2) WR(0,3) \
  RELAXC(1,0) RELAXC(1,1) RELAXC(1,2) RELAXC(1,3) WR(1,0) WR(1,3)                 \
  RELAXC(2,0) RELAXC(2,1) RELAXC(2,2) RELAXC(2,3) WR(2,0) WR(2,3)                 \
  RELAXC(3,0) RELAXC(3,1) RELAXC(3,2) RELAXC(3,3) WR(3,0) WR(3,1) WR(3,2) WR(3,3) \
  __syncthreads(); if (__ballot(ch) == 0ULL) goto relax_done; }

#define UNIT_COLF { float top[6], bot[6], lft[4], rgt[4]; RINGREAD bool ch=false; \
  RELAXC(0,0) RELAXC(1,0) RELAXC(2,0) RELAXC(3,0) WR(0,0) WR(1,0) WR(2,0) WR(3,0) \
  RELAXC(0,1) RELAXC(1,1) RELAXC(2,1) RELAXC(3,1) WR(0,1) WR(3,1)                 \
  RELAXC(0,2) RELAXC(1,2) RELAXC(2,2) RELAXC(3,2) WR(0,2) WR(3,2)                 \
  RELAXC(0,3) RELAXC(1,3) RELAXC(2,3) RELAXC(3,3) WR(0,3) WR(1,3) WR(2,3) WR(3,3) \
  __syncthreads(); if (__ballot(ch) == 0ULL) goto relax_done; }

#define UNIT_ROWB { float top[6], bot[6], lft[4], rgt[4]; RINGREAD bool ch=false; \
  RELAXC(3,3) RELAXC(3,2) RELAXC(3,1) RELAXC(3,0) WR(3,3) WR(3,2) WR(3,1) WR(3,0) \
  RELAXC(2,3) RELAXC(2,2) RELAXC(2,1) RELAXC(2,0) WR(2,3) WR(2,0)                 \
  RELAXC(1,3) RELAXC(1,2) RELAXC(1,1) RELAXC(1,0) WR(1,3) WR(1,0)                 \
  RELAXC(0,3) RELAXC(0,2) RELAXC(0,1) RELAXC(0,0) WR(0,3) WR(0,2) WR(0,1) WR(0,0) \
  __syncthreads(); if (__ballot(ch) == 0ULL) goto relax_done; }

#define UNIT_COLB { float top[6], bot[6], lft[4], rgt[4]; RINGREAD bool ch=false; \
  RELAXC(3,3) RELAXC(2,3) RELAXC(1,3) RELAXC(0,3) WR(3,3) WR(2,3) WR(1,3) WR(0,3) \
  RELAXC(3,2) RELAXC(2,2) RELAXC(1,2) RELAXC(0,2) WR(3,2) WR(0,2)                 \
  RELAXC(3,1) RELAXC(2,1) RELAXC(1,1) RELAXC(0,1) WR(3,1) WR(0,1)                 \
  RELAXC(3,0) RELAXC(2,0) RELAXC(1,0) RELAXC(0,0) WR(3,0) WR(2,0) WR(1,0) WR(0,0) \
  __syncthreads(); if (__ballot(ch) == 0ULL) goto relax_done; }

__global__ __launch_bounds__(64)
void bbastar_kernel(const float* __restrict__ weights,
                    const int* __restrict__ source,
                    const int* __restrict__ target,
                    float* __restrict__ out) {
    __shared__ alignas(16) float d[NP];

    const int b   = blockIdx.x;
    const int tid = threadIdx.x;       // 0..63, single wave
    const int tr  = tid >> 3;
    const int tc  = tid & 7;
    const int r0  = tr << 2;
    const int c0  = tc << 2;
    const int base = (r0 + 1) * P + (c0 + 1);   // LDS addr of cell (r0,c0)

    const int sr  = source[2 * b];
    const int sc  = source[2 * b + 1];

    // weight tile -> registers (float4, aligned), +EPS (matches reference)
    float w[4][4], t[4][4];
    const float* wb = weights + b * (GH * GW);
    #pragma unroll
    for (int i = 0; i < 4; ++i) {
        const float4 v = *(const float4*)(wb + (r0 + i) * GW + c0);
        w[i][0] = v.x + EPSV; w[i][1] = v.y + EPSV;
        w[i][2] = v.z + EPSV; w[i][3] = v.w + EPSV;
    }

    // zero this batch's output region (harness poisons d_out with 0xAA)
    float4* ob4 = (float4*)(out + b * (GH * GW));
    #pragma unroll
    for (int k = 0; k < 4; ++k) ob4[tid + 64 * k] = make_float4(0.f, 0.f, 0.f, 0.f);

    // dist: INF everywhere (incl. permanent halo), float4 stores
    {
        float4* d4 = (float4*)d;
        #pragma unroll
        for (int i = tid; i < NP / 4; i += 64)
            d4[i] = make_float4(INFV, INFV, INFV, INFV);
    }
    #pragma unroll
    for (int i = 0; i < 4; ++i)
        #pragma unroll
        for (int j = 0; j < 4; ++j) t[i][j] = INFV;
    __syncthreads();

    // source = w[source] (owner lane, static register indexing + one LDS write)
    #pragma unroll
    for (int i = 0; i < 4; ++i)
        #pragma unroll
        for (int j = 0; j < 4; ++j)
            if (sr == r0 + i && sc == c0 + j) {
                t[i][j] = w[i][j];
                d[base + i * P + j] = w[i][j];
            }
    __syncthreads();

    for (int cyc = 0; cyc < 1024; ++cyc) {
        UNIT_ROWF
        UNIT_COLF
        UNIT_ROWB
        UNIT_COLB
    }
relax_done: ;

    // publish full tiles for the backtrack
    #pragma unroll
    for (int i = 0; i < 4; ++i)
        #pragma unroll
        for (int j = 0; j < 4; ++j)
            d[base + i * P + j] = t[i][j];
    __syncthreads();

    // Greedy backtrack, lane 0 only. Halo cells are exactly INFV = the
    // reference's where(valid, dvals, INF); strict '<' scan in OFFS order
    // replicates jnp.argmin first-min tie-breaking.
    if (tid == 0) {
        const int drr[8] = {-1, -1, -1,  0, 0,  1, 1, 1};
        const int dcc[8] = {-1,  0,  1, -1, 1, -1, 0, 1};
        int pr = target[2 * b];
        int pc = target[2 * b + 1];
        float* ob = out + b * (GH * GW);
        for (int step = 0; step < GH * GW; ++step) {
            ob[pr * GW + pc] = 1.0f;
            if (pr == sr && pc == sc) break;
            float best = INFV;
            int bj = 0;
            #pragma unroll
            for (int j = 0; j < 8; ++j) {
                const float vv = d[(pr + drr[j] + 1) * P + (pc + dcc[j] + 1)];
                if (vv < best) { best = vv; bj = j; }
            }
            pr += drr[bj];
            pc += dcc[bj];
        }
    }
}

extern "C" void kernel_launch(void* const* d_in, const int* in_sizes, int n_in,
                              void* d_out, int out_size, void* d_ws, size_t ws_size,
                              hipStream_t stream) {
    const float* weights = (const float*)d_in[0];
    const int*   source  = (const int*)d_in[1];
    const int*   target  = (const int*)d_in[2];
    float*       out     = (float*)d_out;
    const int B = in_sizes[0] / (GH * GW);
    bbastar_kernel<<<B, 64, 0, stream>>>(weights, source, target, out);
}

// Round 7
// 73.668 us; speedup vs baseline: 1.0545x; 1.0545x over previous
//
#include <hip/hip_runtime.h>

#define GH 32
#define GW 32
#define P  34              // 32 + 2 halo; halo stays INF forever (OOB + ring + backtrack)
#define NP (P * P)         // 1156, divisible by 4
#define INFV 1000000000.0f
#define EPSV 1e-6f

// One wave (64 lanes) per batch. Lane owns a 4x4 register tile:
// tr = tid>>3, tc = tid&7; origin (r0,c0) = (tr*4, tc*4).
// LDS d[34][34] = dist field with a permanent-INF halo (no boundary selects).
// Unit = { ring-read (20 LDS) ; 16-cell in-place Gauss-Seidel (fwd or bwd
// raster) ; border-write (12 LDS) ; barrier }. (= the round-5 structure.)
//
// Windowed certified early exit (Dijkstra threshold): every unit tracks
// cm = min over values CHANGED (strict decreases) by this lane during the
// current 4-unit window. The window's last unit also publishes the tile
// interior, so d[target] is exact; all lanes broadcast-read it (1 LDS op).
// Exit when NO lane changed a value <= d[target] during the window.
//   Soundness: claim all post-window changes are > dtgt. Induction: a change
//   at y in unit u reads a neighbor value v; if v changed in-window or later,
//   v > dtgt (tracking / induction) so w+v > dtgt; if v is pre-window, y
//   already relaxed against exactly v in the window's first unit (every unit
//   relaxes every cell against all 8 neighbors; borders re-read each unit,
//   register neighbors always current), so w+v >= y's current value — not a
//   change. Hence dtgt is final and every cell whose final value <= dtgt
//   already holds it (a pending improvement would be a future write <= dtgt).
//   The backtrack winner chain has final values <= dtgt (dist decreases from
//   target to source along it), so every winner is exact; non-winners are
//   only inflated, which cannot steal a first-strict-min (for j < j*:
//   v_j >= final_j > v_j*; for j > j*: v_j >= v_j* never wins '<').
//   Therefore the path equals the reference's fully-converged argmin path,
//   including tie-breaking. Termination: at the full fixed point cm = INFV
//   and dtgt < INFV (grid connected), so the exit always triggers.
//
// Backtrack acceleration: after convergence, all 64 lanes precompute each
// cell's first-strict-min neighbor index (OFFS order, halo = INF — identical
// decision to the reference's argmin on the final field) into dirs[]; the
// lane-0 walk is then 1 byte LDS read + a few VALU per step. Only winner
// cells' dirs are consulted, and those are exact (see above).

#define NBRS(i,j) \
    const float ul = ((i)==0) ? top[(j)]   : (((j)==0) ? lft[(i)-1] : t[(i)-1][(j)-1]); \
    const float uu = ((i)==0) ? top[(j)+1] : t[(i)-1][(j)];                    \
    const float ur = ((i)==0) ? top[(j)+2] : (((j)==3) ? rgt[(i)-1] : t[(i)-1][(j)+1]); \
    const float ll = ((j)==0) ? lft[(i)]   : t[(i)][(j)-1];                    \
    const float rr = ((j)==3) ? rgt[(i)]   : t[(i)][(j)+1];                    \
    const float dl = ((i)==3) ? bot[(j)]   : (((j)==0) ? lft[(i)+1] : t[(i)+1][(j)-1]); \
    const float dd = ((i)==3) ? bot[(j)+1] : t[(i)+1][(j)];                    \
    const float dr = ((i)==3) ? bot[(j)+2] : (((j)==3) ? rgt[(i)+1] : t[(i)+1][(j)+1]);

#define NMIN8 \
    fminf(fminf(fminf(fminf(ul,uu),ur), fminf(fminf(ll,rr),dl)), fminf(dd,dr))

#define RELAXT(i,j) { NBRS(i,j)                                               \
    const float old = t[(i)][(j)];                                            \
    const float nd  = w[(i)][(j)] + NMIN8;                                    \
    cm = fminf(cm, (nd < old) ? nd : INFV);                                   \
    t[(i)][(j)] = fminf(old, nd); }

#define RINGREAD                                                              \
    _Pragma("unroll")                                                         \
    for (int k = 0; k < 6; ++k) {                                             \
        top[k] = d[base - P - 1 + k];                                         \
        bot[k] = d[base + 4 * P - 1 + k];                                     \
    }                                                                         \
    _Pragma("unroll")                                                         \
    for (int i = 0; i < 4; ++i) {                                             \
        lft[i] = d[base + i * P - 1];                                         \
        rgt[i] = d[base + i * P + 4];                                         \
    }

#define WR(i,j) d[base + (i)*P + (j)] = t[(i)][(j)];

#define BORDERWRITE                                                           \
    _Pragma("unroll")                                                         \
    for (int j = 0; j < 4; ++j) {                                             \
        d[base + j]         = t[0][j];                                        \
        d[base + 3 * P + j] = t[3][j];                                        \
    }                                                                         \
    d[base + P]         = t[1][0];                                            \
    d[base + 2 * P]     = t[2][0];                                            \
    d[base + P + 3]     = t[1][3];                                            \
    d[base + 2 * P + 3] = t[2][3];

#define UNITF { float top[6], bot[6], lft[4], rgt[4]; RINGREAD                \
    _Pragma("unroll") for (int i = 0; i < 4; ++i)                             \
    _Pragma("unroll") for (int j = 0; j < 4; ++j) RELAXT(i, j)                \
    BORDERWRITE __syncthreads(); }

#define UNITB { float top[6], bot[6], lft[4], rgt[4]; RINGREAD                \
    _Pragma("unroll") for (int i = 3; i >= 0; --i)                            \
    _Pragma("unroll") for (int j = 3; j >= 0; --j) RELAXT(i, j)               \
    BORDERWRITE __syncthreads(); }

#define UNITB_PUB { float top[6], bot[6], lft[4], rgt[4]; RINGREAD            \
    _Pragma("unroll") for (int i = 3; i >= 0; --i)                            \
    _Pragma("unroll") for (int j = 3; j >= 0; --j) RELAXT(i, j)               \
    BORDERWRITE WR(1,1) WR(1,2) WR(2,1) WR(2,2) __syncthreads(); }

#define DIRC(i,j) { NBRS(i,j)                                                 \
    float best = ul; int bj = 0;                                              \
    if (uu < best) { best = uu; bj = 1; }                                     \
    if (ur < best) { best = ur; bj = 2; }                                     \
    if (ll < best) { best = ll; bj = 3; }                                     \
    if (rr < best) { best = rr; bj = 4; }                                     \
    if (dl < best) { best = dl; bj = 5; }                                     \
    if (dd < best) { best = dd; bj = 6; }                                     \
    if (dr < best) { best = dr; bj = 7; }                                     \
    dirs[(r0 + (i)) * GW + (c0 + (j))] = (unsigned char)bj; }

__global__ __launch_bounds__(64)
void bbastar_kernel(const float* __restrict__ weights,
                    const int* __restrict__ source,
                    const int* __restrict__ target,
                    float* __restrict__ out) {
    __shared__ alignas(16) float d[NP];
    __shared__ unsigned char dirs[GH * GW];

    const int b   = blockIdx.x;
    const int tid = threadIdx.x;       // 0..63, single wave
    const int tr  = tid >> 3;
    const int tc  = tid & 7;
    const int r0  = tr << 2;
    const int c0  = tc << 2;
    const int base = (r0 + 1) * P + (c0 + 1);   // LDS addr of cell (r0,c0)

    const int sr  = source[2 * b];
    const int sc  = source[2 * b + 1];
    const int tgr = target[2 * b];
    const int tgc = target[2 * b + 1];
    const int tga = (tgr + 1) * P + (tgc + 1);  // LDS addr of target

    // weight tile -> registers (float4, aligned), +EPS (matches reference)
    float w[4][4], t[4][4];
    const float* wb = weights + b * (GH * GW);
    #pragma unroll
    for (int i = 0; i < 4; ++i) {
        const float4 v = *(const float4*)(wb + (r0 + i) * GW + c0);
        w[i][0] = v.x + EPSV; w[i][1] = v.y + EPSV;
        w[i][2] = v.z + EPSV; w[i][3] = v.w + EPSV;
    }

    // zero this batch's output region (harness poisons d_out with 0xAA)
    float4* ob4 = (float4*)(out + b * (GH * GW));
    #pragma unroll
    for (int k = 0; k < 4; ++k) ob4[tid + 64 * k] = make_float4(0.f, 0.f, 0.f, 0.f);

    // dist: INF everywhere (incl. permanent halo), float4 stores
    {
        float4* d4 = (float4*)d;
        #pragma unroll
        for (int i = tid; i < NP / 4; i += 64)
            d4[i] = make_float4(INFV, INFV, INFV, INFV);
    }
    #pragma unroll
    for (int i = 0; i < 4; ++i)
        #pragma unroll
        for (int j = 0; j < 4; ++j) t[i][j] = INFV;
    __syncthreads();

    // source = w[source] (owner lane, static register indexing + one LDS write)
    #pragma unroll
    for (int i = 0; i < 4; ++i)
        #pragma unroll
        for (int j = 0; j < 4; ++j)
            if (sr == r0 + i && sc == c0 + j) {
                t[i][j] = w[i][j];
                d[base + i * P + j] = w[i][j];
            }
    __syncthreads();

    float cm = INFV;                   // min changed value in current window
    for (int win = 0; win < 1024; ++win) {
        UNITF
        UNITB
        UNITF
        UNITB_PUB
        const float dt = d[tga];       // broadcast read, exact post-window
        if (__ballot(cm <= dt) == 0ULL) break;   // all changes > dtgt => done
        cm = INFV;
    }

    // full publish for dirs precompute + backtrack
    #pragma unroll
    for (int i = 0; i < 4; ++i)
        #pragma unroll
        for (int j = 0; j < 4; ++j) WR(i, j)
    __syncthreads();

    // parallel per-cell argmin-direction precompute (identical first-strict-
    // min OFFS-order decision as the reference, on the final field)
    {
        float top[6], bot[6], lft[4], rgt[4];
        RINGREAD
        #pragma unroll
        for (int i = 0; i < 4; ++i)
            #pragma unroll
            for (int j = 0; j < 4; ++j) DIRC(i, j)
    }
    __syncthreads();

    // Greedy backtrack, lane 0 only: 1 byte LDS read + ~8 VALU per step.
    // row delta: -1 for dir 0,1,2 (0x07); +1 for 5,6,7 (0xE0).
    // col delta: -1 for dir 0,3,5 (0x29); +1 for 2,4,7 (0x94).
    if (tid == 0) {
        int pr = tgr;
        int pc = tgc;
        float* ob = out + b * (GH * GW);
        for (int step = 0; step < GH * GW; ++step) {
            ob[pr * GW + pc] = 1.0f;
            if (pr == sr && pc == sc) break;
            const int bj = dirs[pr * GW + pc];
            pr += ((0xE0 >> bj) & 1) - ((0x07 >> bj) & 1);
            pc += ((0x94 >> bj) & 1) - ((0x29 >> bj) & 1);
        }
    }
}

extern "C" void kernel_launch(void* const* d_in, const int* in_sizes, int n_in,
                              void* d_out, int out_size, void* d_ws, size_t ws_size,
                              hipStream_t stream) {
    const float* weights = (const float*)d_in[0];
    const int*   source  = (const int*)d_in[1];
    const int*   target  = (const int*)d_in[2];
    float*       out     = (float*)d_out;
    const int B = in_sizes[0] / (GH * GW);
    bbastar_kernel<<<B, 64, 0, stream>>>(weights, source, target, out);
}

// Round 8
// 73.494 us; speedup vs baseline: 1.0570x; 1.0024x over previous
//
#include <hip/hip_runtime.h>

#define GH 32
#define GW 32
#define P  34              // 32 + 2 halo; halo stays INF forever (OOB + ring + backtrack)
#define NP (P * P)         // 1156, divisible by 4
#define INFV 1000000000.0f
#define EPSV 1e-6f

// One wave (64 lanes) per batch. Lane owns a 4x4 register tile:
// tr = tid>>3, tc = tid&7; origin (r0,c0) = (tr*4, tc*4).
// LDS d[34][34] = dist field with a permanent-INF halo (no boundary selects).
// Unit = { ring-read (14 LDS: 6x b64 + 8x b32) ; 4 interior cells FIRST
// (register-only neighbors — hides the ring-read lgkmcnt stall) ; 12 border
// cells in fwd/bwd raster ; border-write (12 LDS) ; barrier }.
//
// Windowed certified early exit (Dijkstra threshold): every unit tracks
// cm = min over values CHANGED (strict decreases) by this lane during the
// current 4-unit window. The window's last unit also publishes the tile
// interior, so d[target] is exact; all lanes broadcast-read it (1 LDS op).
// Exit when NO lane changed a value <= d[target] during the window.
//   Soundness: claim all post-window changes are > dtgt. Induction: a change
//   at y in unit u reads a neighbor value v; if v changed in-window or later,
//   v > dtgt (tracking / induction) so w+v > dtgt; if v is pre-window, y
//   already relaxed against exactly v in the window's first unit (every unit
//   relaxes every cell against all 8 neighbors; borders re-read each unit,
//   register neighbors always current), so w+v >= y's current value — not a
//   change. Hence dtgt is final and every cell whose final value <= dtgt
//   already holds it (a pending improvement would be a future write <= dtgt).
//   The backtrack winner chain has final values <= dtgt (dist decreases from
//   target to source along it), so every winner is exact; non-winners are
//   only inflated, which cannot steal a first-strict-min (for j < j*:
//   v_j >= final_j > v_j*; for j > j*: v_j >= v_j* never wins '<').
//   Therefore the path equals the reference's fully-converged argmin path,
//   including tie-breaking. Termination: at the full fixed point cm = INFV
//   and dtgt < INFV (grid connected), so the exit always triggers.
//
// Backtrack: after convergence all 64 lanes precompute each cell's
// first-strict-min neighbor index (OFFS order, halo = INF — identical
// decision to the reference's argmin on the final field) into dirs[];
// the lane-0 walk is 1 byte LDS read + a few VALU per step. Only winner
// cells' dirs are consulted, and those are exact (see above).

#define NBRS(i,j) \
    const float ul = ((i)==0) ? top[(j)]   : (((j)==0) ? lft[(i)-1] : t[(i)-1][(j)-1]); \
    const float uu = ((i)==0) ? top[(j)+1] : t[(i)-1][(j)];                    \
    const float ur = ((i)==0) ? top[(j)+2] : (((j)==3) ? rgt[(i)-1] : t[(i)-1][(j)+1]); \
    const float ll = ((j)==0) ? lft[(i)]   : t[(i)][(j)-1];                    \
    const float rr = ((j)==3) ? rgt[(i)]   : t[(i)][(j)+1];                    \
    const float dl = ((i)==3) ? bot[(j)]   : (((j)==0) ? lft[(i)+1] : t[(i)+1][(j)-1]); \
    const float dd = ((i)==3) ? bot[(j)+1] : t[(i)+1][(j)];                    \
    const float dr = ((i)==3) ? bot[(j)+2] : (((j)==3) ? rgt[(i)+1] : t[(i)+1][(j)+1]);

#define NMIN8 \
    fminf(fminf(fminf(fminf(ul,uu),ur), fminf(fminf(ll,rr),dl)), fminf(dd,dr))

#define RELAXT(i,j) { NBRS(i,j)                                               \
    const float old = t[(i)][(j)];                                            \
    const float nd  = w[(i)][(j)] + NMIN8;                                    \
    cm = fminf(cm, (nd < old) ? nd : INFV);                                   \
    t[(i)][(j)] = fminf(old, nd); }

// top/bot rows start at even element indices (base-P-1 = r0*34+c0,
// base+4P-1 = (r0+5)*34+c0, r0/c0 even) -> three 8B-aligned float2 each.
#define RINGREAD {                                                            \
    const float2 t0 = *(const float2*)&d[base - P - 1];                       \
    const float2 t1 = *(const float2*)&d[base - P + 1];                       \
    const float2 t2 = *(const float2*)&d[base - P + 3];                       \
    top[0]=t0.x; top[1]=t0.y; top[2]=t1.x; top[3]=t1.y; top[4]=t2.x; top[5]=t2.y; \
    const float2 b0 = *(const float2*)&d[base + 4*P - 1];                     \
    const float2 b1 = *(const float2*)&d[base + 4*P + 1];                     \
    const float2 b2 = *(const float2*)&d[base + 4*P + 3];                     \
    bot[0]=b0.x; bot[1]=b0.y; bot[2]=b1.x; bot[3]=b1.y; bot[4]=b2.x; bot[5]=b2.y; \
    lft[0]=d[base-1];   lft[1]=d[base+P-1];   lft[2]=d[base+2*P-1]; lft[3]=d[base+3*P-1]; \
    rgt[0]=d[base+4];   rgt[1]=d[base+P+4];   rgt[2]=d[base+2*P+4]; rgt[3]=d[base+3*P+4]; \
}

#define WR(i,j) d[base + (i)*P + (j)] = t[(i)][(j)];

#define BORDERWRITE                                                           \
    _Pragma("unroll")                                                         \
    for (int j = 0; j < 4; ++j) {                                             \
        d[base + j]         = t[0][j];                                        \
        d[base + 3 * P + j] = t[3][j];                                        \
    }                                                                         \
    d[base + P]         = t[1][0];                                            \
    d[base + 2 * P]     = t[2][0];                                            \
    d[base + P + 3]     = t[1][3];                                            \
    d[base + 2 * P + 3] = t[2][3];

// interior 2x2 first (register-only neighbors; overlaps ring-read latency),
// then the 12 border cells in raster order.
#define UNITF { float top[6], bot[6], lft[4], rgt[4]; RINGREAD                \
    RELAXT(1,1) RELAXT(1,2) RELAXT(2,1) RELAXT(2,2)                           \
    RELAXT(0,0) RELAXT(0,1) RELAXT(0,2) RELAXT(0,3)                           \
    RELAXT(1,0) RELAXT(1,3)                                                   \
    RELAXT(2,0) RELAXT(2,3)                                                   \
    RELAXT(3,0) RELAXT(3,1) RELAXT(3,2) RELAXT(3,3)                           \
    BORDERWRITE __syncthreads(); }

#define UNITB_BODY { float top[6], bot[6], lft[4], rgt[4]; RINGREAD           \
    RELAXT(2,2) RELAXT(2,1) RELAXT(1,2) RELAXT(1,1)                           \
    RELAXT(3,3) RELAXT(3,2) RELAXT(3,1) RELAXT(3,0)                           \
    RELAXT(2,3) RELAXT(2,0)                                                   \
    RELAXT(1,3) RELAXT(1,0)                                                   \
    RELAXT(0,3) RELAXT(0,2) RELAXT(0,1) RELAXT(0,0)                           \
    BORDERWRITE

#define UNITB UNITB_BODY __syncthreads(); }

#define UNITB_PUB UNITB_BODY WR(1,1) WR(1,2) WR(2,1) WR(2,2) __syncthreads(); }

#define DIRC(i,j) { NBRS(i,j)                                                 \
    float best = ul; int bj = 0;                                              \
    if (uu < best) { best = uu; bj = 1; }                                     \
    if (ur < best) { best = ur; bj = 2; }                                     \
    if (ll < best) { best = ll; bj = 3; }                                     \
    if (rr < best) { best = rr; bj = 4; }                                     \
    if (dl < best) { best = dl; bj = 5; }                                     \
    if (dd < best) { best = dd; bj = 6; }                                     \
    if (dr < best) { best = dr; bj = 7; }                                     \
    dirs[(r0 + (i)) * GW + (c0 + (j))] = (unsigned char)bj; }

__global__ __launch_bounds__(64)
void bbastar_kernel(const float* __restrict__ weights,
                    const int* __restrict__ source,
                    const int* __restrict__ target,
                    float* __restrict__ out) {
    __shared__ alignas(16) float d[NP];
    __shared__ unsigned char dirs[GH * GW];

    const int b   = blockIdx.x;
    const int tid = threadIdx.x;       // 0..63, single wave
    const int tr  = tid >> 3;
    const int tc  = tid & 7;
    const int r0  = tr << 2;
    const int c0  = tc << 2;
    const int base = (r0 + 1) * P + (c0 + 1);   // LDS addr of cell (r0,c0)

    const int sr  = source[2 * b];
    const int sc  = source[2 * b + 1];
    const int tgr = target[2 * b];
    const int tgc = target[2 * b + 1];
    const int tga = (tgr + 1) * P + (tgc + 1);  // LDS addr of target

    // weight tile -> registers (float4, aligned), +EPS (matches reference)
    float w[4][4], t[4][4];
    const float* wb = weights + b * (GH * GW);
    #pragma unroll
    for (int i = 0; i < 4; ++i) {
        const float4 v = *(const float4*)(wb + (r0 + i) * GW + c0);
        w[i][0] = v.x + EPSV; w[i][1] = v.y + EPSV;
        w[i][2] = v.z + EPSV; w[i][3] = v.w + EPSV;
    }

    // zero this batch's output region (harness poisons d_out with 0xAA)
    float4* ob4 = (float4*)(out + b * (GH * GW));
    #pragma unroll
    for (int k = 0; k < 4; ++k) ob4[tid + 64 * k] = make_float4(0.f, 0.f, 0.f, 0.f);

    // dist: INF everywhere (incl. permanent halo), float4 stores
    {
        float4* d4 = (float4*)d;
        #pragma unroll
        for (int i = tid; i < NP / 4; i += 64)
            d4[i] = make_float4(INFV, INFV, INFV, INFV);
    }
    #pragma unroll
    for (int i = 0; i < 4; ++i)
        #pragma unroll
        for (int j = 0; j < 4; ++j) t[i][j] = INFV;
    __syncthreads();

    // source = w[source] (owner lane, static register indexing + one LDS write)
    #pragma unroll
    for (int i = 0; i < 4; ++i)
        #pragma unroll
        for (int j = 0; j < 4; ++j)
            if (sr == r0 + i && sc == c0 + j) {
                t[i][j] = w[i][j];
                d[base + i * P + j] = w[i][j];
            }
    __syncthreads();

    float cm = INFV;                   // min changed value in current window
    for (int win = 0; win < 1024; ++win) {
        UNITF
        UNITB
        UNITF
        UNITB_PUB
        const float dt = d[tga];       // broadcast read, exact post-window
        if (__ballot(cm <= dt) == 0ULL) break;   // all changes > dtgt => done
        cm = INFV;
    }

    // full publish for dirs precompute + backtrack
    #pragma unroll
    for (int i = 0; i < 4; ++i)
        #pragma unroll
        for (int j = 0; j < 4; ++j) WR(i, j)
    __syncthreads();

    // parallel per-cell argmin-direction precompute (identical first-strict-
    // min OFFS-order decision as the reference, on the final field)
    {
        float top[6], bot[6], lft[4], rgt[4];
        RINGREAD
        #pragma unroll
        for (int i = 0; i < 4; ++i)
            #pragma unroll
            for (int j = 0; j < 4; ++j) DIRC(i, j)
    }
    __syncthreads();

    // Greedy backtrack, lane 0 only: 1 byte LDS read + ~8 VALU per step.
    // row delta: -1 for dir 0,1,2 (0x07); +1 for 5,6,7 (0xE0).
    // col delta: -1 for dir 0,3,5 (0x29); +1 for 2,4,7 (0x94).
    if (tid == 0) {
        int pr = tgr;
        int pc = tgc;
        float* ob = out + b * (GH * GW);
        for (int step = 0; step < GH * GW; ++step) {
            ob[pr * GW + pc] = 1.0f;
            if (pr == sr && pc == sc) break;
            const int bj = dirs[pr * GW + pc];
            pr += ((0xE0 >> bj) & 1) - ((0x07 >> bj) & 1);
            pc += ((0x94 >> bj) & 1) - ((0x29 >> bj) & 1);
        }
    }
}

extern "C" void kernel_launch(void* const* d_in, const int* in_sizes, int n_in,
                              void* d_out, int out_size, void* d_ws, size_t ws_size,
                              hipStream_t stream) {
    const float* weights = (const float*)d_in[0];
    const int*   source  = (const int*)d_in[1];
    const int*   target  = (const int*)d_in[2];
    float*       out     = (float*)d_out;
    const int B = in_sizes[0] / (GH * GW);
    bbastar_kernel<<<B, 64, 0, stream>>>(weights, source, target, out);
}